// Round 8
// baseline (657.528 us; speedup 1.0000x reference)
//
#include <hip/hip_runtime.h>
#include <math.h>

#define NPFS   4
#define NFM    512
#define NP     256
#define BATCH  128
#define NBLK   (BATCH * NPFS)   // 512 pfaffians
#define THREADS 1024
#define NWAVES (THREADS / 64)
#define TRI    ((NP * (NP - 1)) / 2)   // 32640 strict-lower elements
#define NB     4                 // steps per panel block -> rank-8 trailing update
#define BSTEPS (2 * NB)          // 8 columns consumed per block

typedef _Float16 half_t;
typedef _Float16 h4 __attribute__((ext_vector_type(4)));

// fp16 packed strict-lower triangle, each row padded to a multiple of 4
// elements so every row starts 8B-aligned (h4 loads). rowoff(256) = 33024.
__device__ __forceinline__ int rowoff(int r) {
    int q = r >> 2, rem = r & 3;
    int g = 2 * q * q + q;
    if (rem > 0) g += q;
    if (rem > 1) g += q + 1;
    if (rem > 2) g += q + 1;
    return g << 2;
}

// rank-8 update chain — EXACT jj-ascending order (same form as fp32 kernels)
__device__ __forceinline__ float4 rank8_upd(float4 l, float4 t4, float4 v4,
    const float4 tj0, const float4 tj1, const float4 tj2, const float4 tj3,
    const float4 vj0, const float4 vj1, const float4 vj2, const float4 vj3)
{
    l.x += v4.x * tj0.x - t4.x * vj0.x;
    l.y += v4.x * tj0.y - t4.x * vj0.y;
    l.z += v4.x * tj0.z - t4.x * vj0.z;
    l.w += v4.x * tj0.w - t4.x * vj0.w;
    l.x += v4.y * tj1.x - t4.y * vj1.x;
    l.y += v4.y * tj1.y - t4.y * vj1.y;
    l.z += v4.y * tj1.z - t4.y * vj1.z;
    l.w += v4.y * tj1.w - t4.y * vj1.w;
    l.x += v4.z * tj2.x - t4.z * vj2.x;
    l.y += v4.z * tj2.y - t4.z * vj2.y;
    l.z += v4.z * tj2.z - t4.z * vj2.z;
    l.w += v4.z * tj2.w - t4.z * vj2.w;
    l.x += v4.w * tj3.x - t4.w * vj3.x;
    l.y += v4.w * tj3.y - t4.w * vj3.y;
    l.z += v4.w * tj3.z - t4.w * vj3.z;
    l.w += v4.w * tj3.w - t4.w * vj3.w;
    return l;
}

extern "C" __global__ __launch_bounds__(THREADS, 8)
void MultiPf_32469952758284_kernel(const float* __restrict__ F,
                                   const int* __restrict__ idx,
                                   float* __restrict__ ws)
{
    extern __shared__ char smemc[];
    half_t* Lh    = (half_t*)smemc;                 // 33024 h (66048 B)
    float* Tcol   = (float*)(smemc + 66048);        // NB*256 f (tau_j, col-major)
    float* Vcol   = (float*)(smemc + 70144);        // NB*256 f (v_j, col-major)
    float* colbuf = (float*)(smemc + 74240);        // 256 f (current pivot column)
    int*   idxL   = (int*)(smemc + 75264);          // 256
    // total 76288 B -> TWO blocks/CU co-resident (panel latency of one block
    // overlaps trailing VALU of the other; independent barriers).

    const int tid = threadIdx.x;
    const int bid = blockIdx.x;
    const int b = bid >> 2;   // batch
    const int s = bid & 3;    // pf-state
    const float* __restrict__ Fs = F + (size_t)s * NFM * NFM;

    if (tid < NP) idxL[tid] = idx[b * NP + tid];
    __syncthreads();

    // ---- gather strict lower triangle: A[r][c] = 0.5*(F[ir][ic] - F[ic][ir])
    // L stored fp16; colbuf (pivot-search column) kept fp32.
    for (int e = tid; e < TRI; e += THREADS) {
        int r = (int)((1.0f + sqrtf(1.0f + 8.0f * (float)e)) * 0.5f);
        while (r * (r - 1) / 2 > e) --r;
        while (r * (r + 1) / 2 <= e) ++r;
        int c = e - r * (r - 1) / 2;
        int ir = idxL[r], ic = idxL[c];
        float val = 0.5f * (Fs[(size_t)ir * NFM + ic] - Fs[(size_t)ic * NFM + ir]);
        Lh[rowoff(r) + c] = (half_t)val;
        if (c == 0) colbuf[r] = val;
    }

    float sgn = 1.0f, la = 0.0f;   // maintained on tid<NP; tid 0 writes out

    // per-thread register mirror of this thread's row of the tau/v panels
    float treg[NB], vreg[NB];
    float xpart = 0.0f;            // partial refresh of NEXT step's pivot column
    __syncthreads();

    for (int kb = 0; kb < NP / BSTEPS; ++kb) {
        const int k0 = kb * BSTEPS;

        #pragma unroll
        for (int j = 0; j < NB; ++j) { treg[j] = 0.0f; vreg[j] = 0.0f; }

        // ================= panel: NB steps, lazy trailing =================
        #pragma unroll
        for (int j = 0; j < NB; ++j) {
            const int k = k0 + 2 * j;
            const int p = k + 1;

            float x = 0.0f;
            // ---- A1 (j>0): finish the column-k refresh: xpart (slots <j-1,
            //      computed last A2) + the slot j-1 term (uniform row-k value
            //      written by thread k last A2 -> read post-B3).
            if (j > 0) {
                if (tid > k && tid < NP) {
                    const float tkU = Tcol[(j - 1) * NP + k];
                    const float vkU = Vcol[(j - 1) * NP + k];
                    x = xpart + vreg[j - 1] * tkU - treg[j - 1] * vkU;
                    colbuf[tid] = x;
                }
                __syncthreads();   // B1
            }

            // ---- P2 phase: argmax + uniform panel reads + L column swap.
            // NO LDS panel writes in this phase -> uniform reads race-free.
            int kp = 0; float rpiv = 0.0f, vsw = 0.0f;
            float tkp_u[NB], vkp_u[NB], tP_u[NB], vP_u[NB];
            if (tid < NP) {
                if (j == 0 && tid > k) x = colbuf[tid];   // trailing-seeded

                const int lane = tid & 63;
                const int base = lane << 2;
                // each wave reads the whole column: lane holds rows 4l..4l+3
                const float4 c4 = *(const float4*)(colbuf + base);
                const float xs[4] = {c4.x, c4.y, c4.z, c4.w};
                // wave max of |x| bits over valid rows (32-bit, 6 hops)
                unsigned km = 0u;
                #pragma unroll
                for (int e = 0; e < 4; ++e) {
                    const int r2 = base + e;
                    const unsigned ab = __float_as_uint(xs[e]) & 0x7fffffffu;
                    if (r2 > k && ab > km) km = ab;
                }
                #pragma unroll
                for (int o = 1; o < 64; o <<= 1) {
                    const unsigned ov = (unsigned)__shfl_xor((int)km, o);
                    if (ov > km) km = ov;
                }
                // lowest row holding the max (exact jnp.argmax tie order)
                int cand = 0x7fffffff;
                #pragma unroll
                for (int e = 0; e < 4; ++e) {
                    const int r2 = base + e;
                    const bool c = (r2 > k) &&
                        ((__float_as_uint(xs[e]) & 0x7fffffffu) == km);
                    const unsigned long long mb = __ballot(c);
                    if (mb) {
                        const int rr = ((int)__builtin_ctzll(mb) << 2) + e;
                        if (rr < cand) cand = rr;
                    }
                }
                kp = cand;
                const float cs = colbuf[kp];   // broadcast re-read
                const float piv = -cs;         // piv = A_post[k][k+1] = -L_pre[kp][k]
                rpiv = 1.0f / piv;
                if (kp != p) sgn = -sgn;
                if (piv < 0.0f) sgn = -sgn;
                la += logf(fabsf(piv));

                // uniform pre-swap panel values at rows kp and p.
                #pragma unroll
                for (int jj = 0; jj < NB; ++jj) {
                    if (jj < j) {
                        tkp_u[jj] = Tcol[jj * NP + kp]; vkp_u[jj] = Vcol[jj * NP + kp];
                        tP_u[jj]  = Tcol[jj * NP + p];  vP_u[jj]  = Vcol[jj * NP + p];
                    } else { tkp_u[jj] = vkp_u[jj] = tP_u[jj] = vP_u[jj] = 0.0f; }
                }

                // L column swap p<->kp + post-swap column-p capture (vsw).
                // Each (row,element) touched by exactly one thread -> race-free.
                // Swaps move fp16 values exactly (negation/copy exact).
                const int r = tid;
                if (kp == p) {
                    if (r >= k + 2) vsw = (float)Lh[rowoff(r) + p];
                } else {
                    if (r >= k + 2) {
                        const int orr = rowoff(r);
                        if (r < kp) {
                            const int okp = rowoff(kp);
                            const float a0 = (float)Lh[orr + p];
                            const float a1 = (float)Lh[okp + r];
                            Lh[orr + p] = (half_t)(-a1);
                            Lh[okp + r] = (half_t)(-a0);
                            vsw = -a1;
                        } else if (r == kp) {
                            const float wv = -(float)Lh[orr + p];
                            Lh[orr + p] = (half_t)wv; vsw = wv;
                        } else { // r > kp
                            const half_t t = Lh[orr + p], u2 = Lh[orr + kp];
                            Lh[orr + p] = u2; Lh[orr + kp] = t;
                            vsw = (float)u2;
                        }
                    }
                    // register patch: thread kp's row becomes pre-swap row p.
                    if (tid == kp) {
                        #pragma unroll
                        for (int jj = 0; jj < NB; ++jj)
                            if (jj < j) { treg[jj] = tP_u[jj]; vreg[jj] = vP_u[jj]; }
                    }
                }
            }
            __syncthreads();   // B2

            // ---- A2 phase: extract tau/v (registers + LDS), physical panel
            //      row swap (row kp only), and next step's xpart.
            if (tid < NP) {
                const int r = tid;
                if (r >= k + 2) {
                    const float tau = ((r == kp) ? colbuf[p] : x) * rpiv;
                    float y = vsw;
                    #pragma unroll
                    for (int jj = 0; jj < NB; ++jj)
                        if (jj < j)
                            y += vreg[jj] * tkp_u[jj] - treg[jj] * vkp_u[jj];
                    treg[j] = tau; vreg[j] = y;
                    Tcol[j * NP + r] = tau; Vcol[j * NP + r] = y;

                    if (j < NB - 1) {
                        // partial refresh of column k+2 over slots 0..j-1.
                        // If kn == kp its panel values are being swapped this
                        // phase -> take them from the uniforms (same values).
                        const int kn = k + 2;
                        float xp2 = (float)Lh[rowoff(r) + kn];
                        #pragma unroll
                        for (int jj = 0; jj < NB; ++jj) {
                            if (jj < j) {
                                const float tn = (kn == kp) ? tP_u[jj]
                                                            : Tcol[jj * NP + kn];
                                const float vn = (kn == kp) ? vP_u[jj]
                                                            : Vcol[jj * NP + kn];
                                xp2 += vreg[jj] * tn - treg[jj] * vn;
                            }
                        }
                        xpart = xp2;
                    }
                }
                // physical swap of panel row kp (gets pre-swap row-p values)
                if (kp != p && tid < j) {
                    const int jj = tid;
                    Tcol[jj * NP + kp] = tP_u[jj]; Vcol[jj * NP + kp] = vP_u[jj];
                }
            }
            __syncthreads();   // B3
        }

        // ================= trailing rank-2*NB update =================
        // Lane owns 4 FIXED columns -> tau/v column values preloaded into
        // registers once per block. Per row: 1 h4 read + 1 h4 write of Lh
        // + 8 uniform scalar broadcasts (Tcol/Vcol row values). fp32 chain,
        // single rounding to fp16 at store. Captures column kend -> colbuf
        // (unrounded fp32, consistent across the whole argmax column).
        const int kend = k0 + BSTEPS;   // multiple of 8 -> h4 aligned
        if (kend < NP) {
            const int w = tid >> 6;
            const int lane = tid & 63;
            if (NP - kend > 128) {
                // ---- 1 row per wave-iteration (front half: many columns)
                const int c0 = kend + (lane << 2);
                float4 tj0 = {0,0,0,0}, tj1 = {0,0,0,0}, tj2 = {0,0,0,0}, tj3 = {0,0,0,0};
                float4 vj0 = {0,0,0,0}, vj1 = {0,0,0,0}, vj2 = {0,0,0,0}, vj3 = {0,0,0,0};
                if (c0 < NP) {
                    tj0 = *(const float4*)(Tcol + 0 * NP + c0);
                    tj1 = *(const float4*)(Tcol + 1 * NP + c0);
                    tj2 = *(const float4*)(Tcol + 2 * NP + c0);
                    tj3 = *(const float4*)(Tcol + 3 * NP + c0);
                    vj0 = *(const float4*)(Vcol + 0 * NP + c0);
                    vj1 = *(const float4*)(Vcol + 1 * NP + c0);
                    vj2 = *(const float4*)(Vcol + 2 * NP + c0);
                    vj3 = *(const float4*)(Vcol + 3 * NP + c0);
                }
                for (int r = kend + 1 + w; r < NP; r += NWAVES) {
                    if (c0 < r) {
                        const float4 t4 = {Tcol[0 * NP + r], Tcol[1 * NP + r],
                                           Tcol[2 * NP + r], Tcol[3 * NP + r]};
                        const float4 v4 = {Vcol[0 * NP + r], Vcol[1 * NP + r],
                                           Vcol[2 * NP + r], Vcol[3 * NP + r]};
                        h4* Lp = (h4*)(Lh + rowoff(r) + c0);
                        const h4 lh = *Lp;
                        float4 l = {(float)lh.x, (float)lh.y, (float)lh.z, (float)lh.w};
                        l = rank8_upd(l, t4, v4, tj0, tj1, tj2, tj3,
                                      vj0, vj1, vj2, vj3);
                        h4 oh;
                        oh.x = (half_t)l.x; oh.y = (half_t)l.y;
                        oh.z = (half_t)l.z; oh.w = (half_t)l.w;
                        *Lp = oh;
                        if (lane == 0) colbuf[r] = l.x;   // column kend
                    }
                }
            } else {
                // ---- 2 rows per wave-iteration (back half: <=128 columns):
                // lanes 0-31 -> row r, lanes 32-63 -> row r+1.
                const int sub = lane & 31, hlf = lane >> 5;
                const int c0 = kend + (sub << 2);
                float4 tj0 = {0,0,0,0}, tj1 = {0,0,0,0}, tj2 = {0,0,0,0}, tj3 = {0,0,0,0};
                float4 vj0 = {0,0,0,0}, vj1 = {0,0,0,0}, vj2 = {0,0,0,0}, vj3 = {0,0,0,0};
                if (c0 < NP) {
                    tj0 = *(const float4*)(Tcol + 0 * NP + c0);
                    tj1 = *(const float4*)(Tcol + 1 * NP + c0);
                    tj2 = *(const float4*)(Tcol + 2 * NP + c0);
                    tj3 = *(const float4*)(Tcol + 3 * NP + c0);
                    vj0 = *(const float4*)(Vcol + 0 * NP + c0);
                    vj1 = *(const float4*)(Vcol + 1 * NP + c0);
                    vj2 = *(const float4*)(Vcol + 2 * NP + c0);
                    vj3 = *(const float4*)(Vcol + 3 * NP + c0);
                }
                for (int rr = kend + 1 + 2 * w; rr < NP; rr += 2 * NWAVES) {
                    const int r = rr + hlf;
                    if (r < NP && c0 < r) {
                        const float4 t4 = {Tcol[0 * NP + r], Tcol[1 * NP + r],
                                           Tcol[2 * NP + r], Tcol[3 * NP + r]};
                        const float4 v4 = {Vcol[0 * NP + r], Vcol[1 * NP + r],
                                           Vcol[2 * NP + r], Vcol[3 * NP + r]};
                        h4* Lp = (h4*)(Lh + rowoff(r) + c0);
                        const h4 lh = *Lp;
                        float4 l = {(float)lh.x, (float)lh.y, (float)lh.z, (float)lh.w};
                        l = rank8_upd(l, t4, v4, tj0, tj1, tj2, tj3,
                                      vj0, vj1, vj2, vj3);
                        h4 oh;
                        oh.x = (half_t)l.x; oh.y = (half_t)l.y;
                        oh.z = (half_t)l.z; oh.w = (half_t)l.w;
                        *Lp = oh;
                        if (sub == 0) colbuf[r] = l.x;   // column kend
                    }
                }
            }
        }
        __syncthreads();   // trailing + colbuf visible to next panel
    }

    if (tid == 0) {
        ws[bid * 2 + 0] = sgn;
        ws[bid * 2 + 1] = la;
    }
}

extern "C" __global__ void MultiPf_combine_kernel(const float* __restrict__ ws,
                                                  float* __restrict__ out)
{
    int b = threadIdx.x + blockIdx.x * blockDim.x;
    if (b >= BATCH) return;
    float sg[NPFS], lg[NPFS];
    float m = -INFINITY;
    for (int j = 0; j < NPFS; ++j) {
        sg[j] = ws[(b * NPFS + j) * 2 + 0];
        lg[j] = ws[(b * NPFS + j) * 2 + 1];
        m = fmaxf(m, lg[j]);
    }
    float val = 0.0f;
    for (int j = 0; j < NPFS; ++j)
        val += sg[j] * expf(lg[j] - m);
    float osgn = (val > 0.0f) ? 1.0f : ((val < 0.0f) ? -1.0f : 0.0f);
    out[b]         = osgn;
    out[BATCH + b] = m + logf(fabsf(val));
}

extern "C" void kernel_launch(void* const* d_in, const int* in_sizes, int n_in,
                              void* d_out, int out_size, void* d_ws, size_t ws_size,
                              hipStream_t stream)
{
    (void)in_sizes; (void)n_in; (void)out_size; (void)ws_size;
    const float* F   = (const float*)d_in[0];
    const int*   idx = (const int*)d_in[1];
    float* out = (float*)d_out;
    float* ws  = (float*)d_ws;

    const size_t smem_bytes = 76288;   // see LDS layout in kernel (2 blocks/CU)

    // Raise dynamic-LDS cap above the 64 KB default (gfx950: 160 KB/CU).
    (void)hipFuncSetAttribute((const void*)MultiPf_32469952758284_kernel,
                              hipFuncAttributeMaxDynamicSharedMemorySize,
                              (int)smem_bytes);

    MultiPf_32469952758284_kernel<<<NBLK, THREADS, smem_bytes, stream>>>(F, idx, ws);
    MultiPf_combine_kernel<<<1, 128, 0, stream>>>(ws, out);
}

// Round 9
// 429.487 us; speedup vs baseline: 1.5310x; 1.5310x over previous
//
#include <hip/hip_runtime.h>
#include <math.h>

#define NPFS   4
#define NFM    512
#define NP     256
#define BATCH  128
#define NBLK   (BATCH * NPFS)   // 512 pfaffians
#define THREADS 512
#define NWAVES (THREADS / 64)   // 8
#define TRI    ((NP * (NP - 1)) / 2)   // 32640 strict-lower elements
#define NB     4                 // steps per panel block -> rank-8 trailing update
#define BSTEPS (2 * NB)          // 8 columns consumed per block

typedef _Float16 half_t;
typedef _Float16 h4 __attribute__((ext_vector_type(4)));

// fp16 packed strict-lower triangle, each row padded to a multiple of 4
// elements so every row starts 8B-aligned (h4 loads). rowoff(256) = 33024.
__device__ __forceinline__ int rowoff(int r) {
    int q = r >> 2, rem = r & 3;
    int g = 2 * q * q + q;
    if (rem > 0) g += q;
    if (rem > 1) g += q + 1;
    if (rem > 2) g += q + 1;
    return g << 2;
}

// rank-8 update chain — EXACT jj-ascending order (same form as fp32 kernels)
__device__ __forceinline__ float4 rank8_upd(float4 l, float4 t4, float4 v4,
    const float4 tj0, const float4 tj1, const float4 tj2, const float4 tj3,
    const float4 vj0, const float4 vj1, const float4 vj2, const float4 vj3)
{
    l.x += v4.x * tj0.x - t4.x * vj0.x;
    l.y += v4.x * tj0.y - t4.x * vj0.y;
    l.z += v4.x * tj0.z - t4.x * vj0.z;
    l.w += v4.x * tj0.w - t4.x * vj0.w;
    l.x += v4.y * tj1.x - t4.y * vj1.x;
    l.y += v4.y * tj1.y - t4.y * vj1.y;
    l.z += v4.y * tj1.z - t4.y * vj1.z;
    l.w += v4.y * tj1.w - t4.y * vj1.w;
    l.x += v4.z * tj2.x - t4.z * vj2.x;
    l.y += v4.z * tj2.y - t4.z * vj2.y;
    l.z += v4.z * tj2.z - t4.z * vj2.z;
    l.w += v4.z * tj2.w - t4.z * vj2.w;
    l.x += v4.w * tj3.x - t4.w * vj3.x;
    l.y += v4.w * tj3.y - t4.w * vj3.y;
    l.z += v4.w * tj3.z - t4.w * vj3.z;
    l.w += v4.w * tj3.w - t4.w * vj3.w;
    return l;
}

extern "C" __global__ __launch_bounds__(THREADS, 4)
void MultiPf_32469952758284_kernel(const float* __restrict__ F,
                                   const int* __restrict__ idx,
                                   float* __restrict__ ws)
{
    extern __shared__ char smemc[];
    half_t* Lh    = (half_t*)smemc;                 // 33024 h (66048 B)
    float* Tcol   = (float*)(smemc + 66048);        // NB*256 f (tau_j, col-major)
    float* Vcol   = (float*)(smemc + 70144);        // NB*256 f (v_j, col-major)
    float* colbuf = (float*)(smemc + 74240);        // 256 f (current pivot column)
    int*   idxL   = (int*)(smemc + 75264);          // 256
    // total 76288 B; 512-thread blocks -> TWO blocks/CU co-resident
    // (panel latency of one block overlaps trailing VALU of the other).
    // launch_bounds(512,4): 4 waves/EU -> VGPR cap 128 -> NO scratch spill
    // (round-8's (1024,8) capped at 64 VGPR and spilled 1.9 GB to HBM).

    const int tid = threadIdx.x;
    const int bid = blockIdx.x;
    const int b = bid >> 2;   // batch
    const int s = bid & 3;    // pf-state
    const float* __restrict__ Fs = F + (size_t)s * NFM * NFM;

    if (tid < NP) idxL[tid] = idx[b * NP + tid];
    __syncthreads();

    // ---- gather strict lower triangle: A[r][c] = 0.5*(F[ir][ic] - F[ic][ir])
    // L stored fp16; colbuf (pivot-search column) kept fp32.
    for (int e = tid; e < TRI; e += THREADS) {
        int r = (int)((1.0f + sqrtf(1.0f + 8.0f * (float)e)) * 0.5f);
        while (r * (r - 1) / 2 > e) --r;
        while (r * (r + 1) / 2 <= e) ++r;
        int c = e - r * (r - 1) / 2;
        int ir = idxL[r], ic = idxL[c];
        float val = 0.5f * (Fs[(size_t)ir * NFM + ic] - Fs[(size_t)ic * NFM + ir]);
        Lh[rowoff(r) + c] = (half_t)val;
        if (c == 0) colbuf[r] = val;
    }

    float sgn = 1.0f, la = 0.0f;   // maintained on tid<NP; tid 0 writes out

    // per-thread register mirror of this thread's row of the tau/v panels
    float treg[NB], vreg[NB];
    float xpart = 0.0f;            // partial refresh of NEXT step's pivot column
    __syncthreads();

    for (int kb = 0; kb < NP / BSTEPS; ++kb) {
        const int k0 = kb * BSTEPS;

        #pragma unroll
        for (int j = 0; j < NB; ++j) { treg[j] = 0.0f; vreg[j] = 0.0f; }

        // ================= panel: NB steps, lazy trailing =================
        #pragma unroll
        for (int j = 0; j < NB; ++j) {
            const int k = k0 + 2 * j;
            const int p = k + 1;

            float x = 0.0f;
            // ---- A1 (j>0): finish the column-k refresh: xpart (slots <j-1,
            //      computed last A2) + the slot j-1 term (uniform row-k value
            //      written by thread k last A2 -> read post-B3).
            if (j > 0) {
                if (tid > k && tid < NP) {
                    const float tkU = Tcol[(j - 1) * NP + k];
                    const float vkU = Vcol[(j - 1) * NP + k];
                    x = xpart + vreg[j - 1] * tkU - treg[j - 1] * vkU;
                    colbuf[tid] = x;
                }
                __syncthreads();   // B1
            }

            // ---- P2 phase: argmax + uniform panel reads + L column swap.
            // NO LDS panel writes in this phase -> uniform reads race-free.
            int kp = 0; float rpiv = 0.0f, vsw = 0.0f;
            float tkp_u[NB], vkp_u[NB], tP_u[NB], vP_u[NB];
            if (tid < NP) {
                if (j == 0 && tid > k) x = colbuf[tid];   // trailing-seeded

                const int lane = tid & 63;
                const int base = lane << 2;
                // each wave reads the whole column: lane holds rows 4l..4l+3
                const float4 c4 = *(const float4*)(colbuf + base);
                const float xs[4] = {c4.x, c4.y, c4.z, c4.w};
                // wave max of |x| bits over valid rows (32-bit, 6 hops)
                unsigned km = 0u;
                #pragma unroll
                for (int e = 0; e < 4; ++e) {
                    const int r2 = base + e;
                    const unsigned ab = __float_as_uint(xs[e]) & 0x7fffffffu;
                    if (r2 > k && ab > km) km = ab;
                }
                #pragma unroll
                for (int o = 1; o < 64; o <<= 1) {
                    const unsigned ov = (unsigned)__shfl_xor((int)km, o);
                    if (ov > km) km = ov;
                }
                // lowest row holding the max (exact jnp.argmax tie order)
                int cand = 0x7fffffff;
                #pragma unroll
                for (int e = 0; e < 4; ++e) {
                    const int r2 = base + e;
                    const bool c = (r2 > k) &&
                        ((__float_as_uint(xs[e]) & 0x7fffffffu) == km);
                    const unsigned long long mb = __ballot(c);
                    if (mb) {
                        const int rr = ((int)__builtin_ctzll(mb) << 2) + e;
                        if (rr < cand) cand = rr;
                    }
                }
                kp = cand;
                const float cs = colbuf[kp];   // broadcast re-read
                const float piv = -cs;         // piv = A_post[k][k+1] = -L_pre[kp][k]
                rpiv = 1.0f / piv;
                if (kp != p) sgn = -sgn;
                if (piv < 0.0f) sgn = -sgn;
                la += logf(fabsf(piv));

                // uniform pre-swap panel values at rows kp and p.
                #pragma unroll
                for (int jj = 0; jj < NB; ++jj) {
                    if (jj < j) {
                        tkp_u[jj] = Tcol[jj * NP + kp]; vkp_u[jj] = Vcol[jj * NP + kp];
                        tP_u[jj]  = Tcol[jj * NP + p];  vP_u[jj]  = Vcol[jj * NP + p];
                    } else { tkp_u[jj] = vkp_u[jj] = tP_u[jj] = vP_u[jj] = 0.0f; }
                }

                // L column swap p<->kp + post-swap column-p capture (vsw).
                // Each (row,element) touched by exactly one thread -> race-free.
                // Swaps move fp16 values exactly (negation/copy exact).
                const int r = tid;
                if (kp == p) {
                    if (r >= k + 2) vsw = (float)Lh[rowoff(r) + p];
                } else {
                    if (r >= k + 2) {
                        const int orr = rowoff(r);
                        if (r < kp) {
                            const int okp = rowoff(kp);
                            const float a0 = (float)Lh[orr + p];
                            const float a1 = (float)Lh[okp + r];
                            Lh[orr + p] = (half_t)(-a1);
                            Lh[okp + r] = (half_t)(-a0);
                            vsw = -a1;
                        } else if (r == kp) {
                            const float wv = -(float)Lh[orr + p];
                            Lh[orr + p] = (half_t)wv; vsw = wv;
                        } else { // r > kp
                            const half_t t = Lh[orr + p], u2 = Lh[orr + kp];
                            Lh[orr + p] = u2; Lh[orr + kp] = t;
                            vsw = (float)u2;
                        }
                    }
                    // register patch: thread kp's row becomes pre-swap row p.
                    if (tid == kp) {
                        #pragma unroll
                        for (int jj = 0; jj < NB; ++jj)
                            if (jj < j) { treg[jj] = tP_u[jj]; vreg[jj] = vP_u[jj]; }
                    }
                }
            }
            __syncthreads();   // B2

            // ---- A2 phase: extract tau/v (registers + LDS), physical panel
            //      row swap (row kp only), and next step's xpart.
            if (tid < NP) {
                const int r = tid;
                if (r >= k + 2) {
                    const float tau = ((r == kp) ? colbuf[p] : x) * rpiv;
                    float y = vsw;
                    #pragma unroll
                    for (int jj = 0; jj < NB; ++jj)
                        if (jj < j)
                            y += vreg[jj] * tkp_u[jj] - treg[jj] * vkp_u[jj];
                    treg[j] = tau; vreg[j] = y;
                    Tcol[j * NP + r] = tau; Vcol[j * NP + r] = y;

                    if (j < NB - 1) {
                        // partial refresh of column k+2 over slots 0..j-1.
                        // If kn == kp its panel values are being swapped this
                        // phase -> take them from the uniforms (same values).
                        const int kn = k + 2;
                        float xp2 = (float)Lh[rowoff(r) + kn];
                        #pragma unroll
                        for (int jj = 0; jj < NB; ++jj) {
                            if (jj < j) {
                                const float tn = (kn == kp) ? tP_u[jj]
                                                            : Tcol[jj * NP + kn];
                                const float vn = (kn == kp) ? vP_u[jj]
                                                            : Vcol[jj * NP + kn];
                                xp2 += vreg[jj] * tn - treg[jj] * vn;
                            }
                        }
                        xpart = xp2;
                    }
                }
                // physical swap of panel row kp (gets pre-swap row-p values)
                if (kp != p && tid < j) {
                    const int jj = tid;
                    Tcol[jj * NP + kp] = tP_u[jj]; Vcol[jj * NP + kp] = vP_u[jj];
                }
            }
            __syncthreads();   // B3
        }

        // ================= trailing rank-2*NB update =================
        // Lane owns 4 FIXED columns -> tau/v column values preloaded into
        // registers once per block. Per row: 1 h4 read + 1 h4 write of Lh
        // + 8 uniform scalar broadcasts (Tcol/Vcol row values). fp32 chain,
        // single rounding to fp16 at store. Captures column kend -> colbuf
        // (unrounded fp32, consistent across the whole argmax column).
        const int kend = k0 + BSTEPS;   // multiple of 8 -> h4 aligned
        if (kend < NP) {
            const int w = tid >> 6;
            const int lane = tid & 63;
            if (NP - kend > 128) {
                // ---- 1 row per wave-iteration (front half: many columns)
                const int c0 = kend + (lane << 2);
                float4 tj0 = {0,0,0,0}, tj1 = {0,0,0,0}, tj2 = {0,0,0,0}, tj3 = {0,0,0,0};
                float4 vj0 = {0,0,0,0}, vj1 = {0,0,0,0}, vj2 = {0,0,0,0}, vj3 = {0,0,0,0};
                if (c0 < NP) {
                    tj0 = *(const float4*)(Tcol + 0 * NP + c0);
                    tj1 = *(const float4*)(Tcol + 1 * NP + c0);
                    tj2 = *(const float4*)(Tcol + 2 * NP + c0);
                    tj3 = *(const float4*)(Tcol + 3 * NP + c0);
                    vj0 = *(const float4*)(Vcol + 0 * NP + c0);
                    vj1 = *(const float4*)(Vcol + 1 * NP + c0);
                    vj2 = *(const float4*)(Vcol + 2 * NP + c0);
                    vj3 = *(const float4*)(Vcol + 3 * NP + c0);
                }
                for (int r = kend + 1 + w; r < NP; r += NWAVES) {
                    if (c0 < r) {
                        const float4 t4 = {Tcol[0 * NP + r], Tcol[1 * NP + r],
                                           Tcol[2 * NP + r], Tcol[3 * NP + r]};
                        const float4 v4 = {Vcol[0 * NP + r], Vcol[1 * NP + r],
                                           Vcol[2 * NP + r], Vcol[3 * NP + r]};
                        h4* Lp = (h4*)(Lh + rowoff(r) + c0);
                        const h4 lh = *Lp;
                        float4 l = {(float)lh.x, (float)lh.y, (float)lh.z, (float)lh.w};
                        l = rank8_upd(l, t4, v4, tj0, tj1, tj2, tj3,
                                      vj0, vj1, vj2, vj3);
                        h4 oh;
                        oh.x = (half_t)l.x; oh.y = (half_t)l.y;
                        oh.z = (half_t)l.z; oh.w = (half_t)l.w;
                        *Lp = oh;
                        if (lane == 0) colbuf[r] = l.x;   // column kend
                    }
                }
            } else {
                // ---- 2 rows per wave-iteration (back half: <=128 columns):
                // lanes 0-31 -> row r, lanes 32-63 -> row r+1.
                const int sub = lane & 31, hlf = lane >> 5;
                const int c0 = kend + (sub << 2);
                float4 tj0 = {0,0,0,0}, tj1 = {0,0,0,0}, tj2 = {0,0,0,0}, tj3 = {0,0,0,0};
                float4 vj0 = {0,0,0,0}, vj1 = {0,0,0,0}, vj2 = {0,0,0,0}, vj3 = {0,0,0,0};
                if (c0 < NP) {
                    tj0 = *(const float4*)(Tcol + 0 * NP + c0);
                    tj1 = *(const float4*)(Tcol + 1 * NP + c0);
                    tj2 = *(const float4*)(Tcol + 2 * NP + c0);
                    tj3 = *(const float4*)(Tcol + 3 * NP + c0);
                    vj0 = *(const float4*)(Vcol + 0 * NP + c0);
                    vj1 = *(const float4*)(Vcol + 1 * NP + c0);
                    vj2 = *(const float4*)(Vcol + 2 * NP + c0);
                    vj3 = *(const float4*)(Vcol + 3 * NP + c0);
                }
                for (int rr = kend + 1 + 2 * w; rr < NP; rr += 2 * NWAVES) {
                    const int r = rr + hlf;
                    if (r < NP && c0 < r) {
                        const float4 t4 = {Tcol[0 * NP + r], Tcol[1 * NP + r],
                                           Tcol[2 * NP + r], Tcol[3 * NP + r]};
                        const float4 v4 = {Vcol[0 * NP + r], Vcol[1 * NP + r],
                                           Vcol[2 * NP + r], Vcol[3 * NP + r]};
                        h4* Lp = (h4*)(Lh + rowoff(r) + c0);
                        const h4 lh = *Lp;
                        float4 l = {(float)lh.x, (float)lh.y, (float)lh.z, (float)lh.w};
                        l = rank8_upd(l, t4, v4, tj0, tj1, tj2, tj3,
                                      vj0, vj1, vj2, vj3);
                        h4 oh;
                        oh.x = (half_t)l.x; oh.y = (half_t)l.y;
                        oh.z = (half_t)l.z; oh.w = (half_t)l.w;
                        *Lp = oh;
                        if (sub == 0) colbuf[r] = l.x;   // column kend
                    }
                }
            }
        }
        __syncthreads();   // trailing + colbuf visible to next panel
    }

    if (tid == 0) {
        ws[bid * 2 + 0] = sgn;
        ws[bid * 2 + 1] = la;
    }
}

extern "C" __global__ void MultiPf_combine_kernel(const float* __restrict__ ws,
                                                  float* __restrict__ out)
{
    int b = threadIdx.x + blockIdx.x * blockDim.x;
    if (b >= BATCH) return;
    float sg[NPFS], lg[NPFS];
    float m = -INFINITY;
    for (int j = 0; j < NPFS; ++j) {
        sg[j] = ws[(b * NPFS + j) * 2 + 0];
        lg[j] = ws[(b * NPFS + j) * 2 + 1];
        m = fmaxf(m, lg[j]);
    }
    float val = 0.0f;
    for (int j = 0; j < NPFS; ++j)
        val += sg[j] * expf(lg[j] - m);
    float osgn = (val > 0.0f) ? 1.0f : ((val < 0.0f) ? -1.0f : 0.0f);
    out[b]         = osgn;
    out[BATCH + b] = m + logf(fabsf(val));
}

extern "C" void kernel_launch(void* const* d_in, const int* in_sizes, int n_in,
                              void* d_out, int out_size, void* d_ws, size_t ws_size,
                              hipStream_t stream)
{
    (void)in_sizes; (void)n_in; (void)out_size; (void)ws_size;
    const float* F   = (const float*)d_in[0];
    const int*   idx = (const int*)d_in[1];
    float* out = (float*)d_out;
    float* ws  = (float*)d_ws;

    const size_t smem_bytes = 76288;   // see LDS layout in kernel (2 blocks/CU)

    // Raise dynamic-LDS cap above the 64 KB default (gfx950: 160 KB/CU).
    (void)hipFuncSetAttribute((const void*)MultiPf_32469952758284_kernel,
                              hipFuncAttributeMaxDynamicSharedMemorySize,
                              (int)smem_bytes);

    MultiPf_32469952758284_kernel<<<NBLK, THREADS, smem_bytes, stream>>>(F, idx, ws);
    MultiPf_combine_kernel<<<1, 128, 0, stream>>>(ws, out);
}